// Round 3
// baseline (311.631 us; speedup 1.0000x reference)
//
#include <hip/hip_runtime.h>
#include <math.h>

#define NT    300
#define NA    3
#define BATCH 16
#define NCLS  80
#define CCH   85
#define HASHSZ 2048

// Grid: blocks 0..2 = per-target math (one per layer, 256 thr x 4 rows)
//       blocks 3..1577 = obj softplus sweep, 1 element/thread
//         L0: 1200 blocks (307200 el), L1: 300 (76800), L2: 75 (19200)
#define NB_OBJ 1575
#define NBLK  (NB_OBJ + 3)

// ws layout (doubles): acc[l*4+{0,1,2,3}] = lbox,lcls,obj_corr,nvalid (layer l)
//                      acc[16+l] = obj softplus sum (atomicAdd)
//                      ((int*)acc)[48] = done counter (byte offset 192)
// kernel_launch zeroes the first 256 B each call.

__device__ __forceinline__ float softplusf(float x) {
    // == max(x,0) + log1p(exp(-|x|)) == bce(x, 0)
    return fmaxf(x, 0.f) + log1pf(expf(-fabsf(x)));
}

// 256-thread (4-wave) block reduce; result valid on thread 0
__device__ __forceinline__ double block_reduce(double v, double* red) {
    #pragma unroll
    for (int off = 32; off > 0; off >>= 1)
        v += __shfl_down(v, off, 64);
    const int wid  = threadIdx.x >> 6;
    const int lane = threadIdx.x & 63;
    if (lane == 0) red[wid] = v;
    __syncthreads();
    double r = v;
    if (threadIdx.x < 4) r = red[threadIdx.x];
    r += __shfl_down(r, 2, 64);
    r += __shfl_down(r, 1, 64);
    __syncthreads();   // red reusable after return
    return r;
}

__device__ __forceinline__ void finalize(const double* acc, float* out) {
    double lbox = 0.0, lobj = 0.0, lcls = 0.0;
    for (int l = 0; l < 3; ++l) {
        const double nv = fmax(acc[l*4 + 3], 1.0);
        lbox += acc[l*4 + 0] / nv;
        lcls += acc[l*4 + 1] / (nv * (double)NCLS);
        const double N = (double)((BATCH * NA * 6400) >> (2*l));
        lobj += (acc[16 + l] - acc[l*4 + 2]) / N;
    }
    lbox *= 0.05;
    lcls *= 0.5;
    const double loss = lbox + lobj + lcls;
    out[0] = (float)loss;
    out[1] = (float)lbox;
    out[2] = (float)lobj;
    out[3] = (float)lcls;
    out[4] = (float)loss;
}

__global__ __launch_bounds__(256) void main_kernel(
    const float* __restrict__ p0, const float* __restrict__ p1,
    const float* __restrict__ p2,
    const float* __restrict__ targets, const float* __restrict__ anchors,
    double* __restrict__ acc, float* __restrict__ out)
{
    __shared__ double red[4];
    __shared__ int tkey[HASHSZ];
    __shared__ int trow[HASHSZ];

    if (blockIdx.x >= 3) {
        // ---------- obj softplus sweep: 1 element / thread ----------
        const int bb0 = blockIdx.x - 3;
        int li, bb;
        if (bb0 < 1200)      { li = 0; bb = bb0; }
        else if (bb0 < 1500) { li = 1; bb = bb0 - 1200; }
        else                 { li = 2; bb = bb0 - 1500; }
        const float* p = (li == 0) ? p0 : ((li == 1) ? p1 : p2);
        const int idx = bb * 256 + threadIdx.x;       // exact fit per layer
        const float s = softplusf(p[(size_t)idx * CCH + 4]);
        const double t = block_reduce((double)s, red);
        if (threadIdx.x == 0) atomicAdd(&acc[16 + li], t);
    } else {
        // ---------- per-target math, one block per layer ----------
        const int li = blockIdx.x;
        const float* p = (li == 0) ? p0 : ((li == 1) ? p1 : p2);
        const int W = 80 >> li;
        const int H = W;

        float lbox = 0.f, lcls = 0.f, nval = 0.f, corr = 0.f;
        int   key[4], slot[4];
        float objx[4], iouc[4];

        #pragma unroll
        for (int rr = 0; rr < 4; ++rr) { key[rr] = -1; slot[rr] = -1; objx[rr] = 0.f; iouc[rr] = 0.f; }

        // zero hash
        #pragma unroll
        for (int q = 0; q < HASHSZ / 256; ++q) {
            tkey[threadIdx.x + q*256] = -1;
            trow[threadIdx.x + q*256] = -1;
        }
        __syncthreads();

        #pragma unroll
        for (int rr = 0; rr < 4; ++rr) {
            const int r = threadIdx.x + rr * 256;     // row = a*NT + ti
            if (r >= NA * NT) break;
            const int a  = r / NT;
            const int ti = r - a * NT;
            const float img = targets[ti*6 + 0];
            const float cls = targets[ti*6 + 1];
            const float tx  = targets[ti*6 + 2] * (float)W;
            const float ty  = targets[ti*6 + 3] * (float)H;
            const float tw  = targets[ti*6 + 4] * (float)W;
            const float th  = targets[ti*6 + 5] * (float)H;

            const float ax = anchors[(li*3 + a)*2 + 0];
            const float ay = anchors[(li*3 + a)*2 + 1];
            const float rx = tw / ax, ry = th / ay;
            const float mr = fmaxf(fmaxf(rx, 1.f/rx), fmaxf(ry, 1.f/ry));
            const bool  mask = mr < 4.f;
            const float mf = mask ? 1.f : 0.f;

            const int b = (int)img;
            const int c = (int)cls;
            const int gij_x = (int)tx;                // trunc == floor (positive)
            const int gij_y = (int)ty;
            const int gi = min(max(gij_x, 0), W - 1);
            const int gj = min(max(gij_y, 0), H - 1);

            // reference quirk: anch = anchors[a, a] (layer-independent)
            const float anch_x = anchors[(a*3 + a)*2 + 0];
            const float anch_y = anchors[(a*3 + a)*2 + 1];

            const int match = BATCH - 1 - b;
            const float* ps = p + ((((size_t)match*NA + a)*H + gj)*W + gi) * CCH;

            const float s0 = ps[0], s1 = ps[1], s2 = ps[2], s3 = ps[3];
            objx[rr] = ps[4];

            const float pxx = 1.f / (1.f + expf(-s0));
            const float pyy = 1.f / (1.f + expf(-s1));
            const float pw  = expf(s2) * anch_x;
            const float ph  = expf(s3) * anch_y;
            const float fx  = tx - (float)gij_x;
            const float fy  = ty - (float)gij_y;

            const float eps = 1e-9f;
            const float b1x1 = pxx - pw*0.5f, b1x2 = pxx + pw*0.5f;
            const float b1y1 = pyy - ph*0.5f, b1y2 = pyy + ph*0.5f;
            const float b2x1 = fx - tw*0.5f,  b2x2 = fx + tw*0.5f;
            const float b2y1 = fy - th*0.5f,  b2y2 = fy + th*0.5f;
            float iw = fminf(b1x2, b2x2) - fmaxf(b1x1, b2x1); iw = fmaxf(iw, 0.f);
            float ih = fminf(b1y2, b2y2) - fmaxf(b1y1, b2y1); ih = fmaxf(ih, 0.f);
            const float inter = iw * ih;
            const float w1 = b1x2 - b1x1, h1 = b1y2 - b1y1 + eps;
            const float w2 = b2x2 - b2x1, h2 = b2y2 - b2y1 + eps;
            const float uni = w1*h1 + w2*h2 - inter + eps;
            const float iou = inter / uni;
            const float cw = fmaxf(b1x2, b2x2) - fminf(b1x1, b2x1);
            const float ch = fmaxf(b1y2, b2y2) - fminf(b1y1, b2y1);
            const float c2 = cw*cw + ch*ch + eps;
            const float dx = b2x1 + b2x2 - b1x1 - b1x2;
            const float dy = b2y1 + b2y2 - b1y1 - b1y2;
            const float rho2 = (dx*dx + dy*dy) * 0.25f;
            const float dat = atanf(w2/h2) - atanf(w1/h1);
            const float v = 0.40528473456935108577f * dat * dat;  // 4/pi^2
            const float alpha = v / (1.f + eps - iou + v);
            const float ciou = iou - (rho2/c2 + v*alpha);

            lbox += (1.f - ciou) * mf;
            nval += mf;

            float cls_sum = 0.f;
            #pragma unroll 20
            for (int k = 0; k < NCLS; ++k) cls_sum += softplusf(ps[5 + k]);
            cls_sum -= ps[5 + c];
            lcls += cls_sum * mf;

            if (mask) {
                key[rr]  = ((match*NA + a)*H + gj)*W + gi;
                iouc[rr] = fmaxf(ciou, 0.f);
            }
        }

        // last-wins dedup via LDS hash (key -> max row)
        #pragma unroll
        for (int rr = 0; rr < 4; ++rr) {
            if (key[rr] < 0) continue;
            const int r = threadIdx.x + rr * 256;
            unsigned h = ((unsigned)key[rr] * 2654435761u) >> 21;
            int s = (int)(h & (HASHSZ - 1));
            while (true) {
                const int prev = atomicCAS(&tkey[s], -1, key[rr]);
                if (prev == -1 || prev == key[rr]) {
                    atomicMax(&trow[s], r);
                    slot[rr] = s;
                    break;
                }
                s = (s + 1) & (HASHSZ - 1);
            }
        }
        __syncthreads();
        #pragma unroll
        for (int rr = 0; rr < 4; ++rr) {
            const int r = threadIdx.x + rr * 256;
            if (key[rr] >= 0 && trow[slot[rr]] == r)
                corr += objx[rr] * iouc[rr];   // bce(x,t)-bce(x,0) = -x*t
        }

        const double vb = block_reduce((double)lbox, red);
        const double vc = block_reduce((double)lcls, red);
        const double vo = block_reduce((double)corr, red);
        const double vn = block_reduce((double)nval, red);
        if (threadIdx.x == 0) {
            acc[li*4 + 0] = vb;
            acc[li*4 + 1] = vc;
            acc[li*4 + 2] = vo;
            acc[li*4 + 3] = vn;
        }
    }

    // ---------- last block finalizes ----------
    __syncthreads();
    if (threadIdx.x == 0) {
        __threadfence();
        int* cnt = (int*)(acc + 24);
        const int done = atomicAdd(cnt, 1);
        if (done == NBLK - 1) {
            __threadfence();
            finalize(acc, out);
        }
    }
}

extern "C" void kernel_launch(void* const* d_in, const int* in_sizes, int n_in,
                              void* d_out, int out_size, void* d_ws, size_t ws_size,
                              hipStream_t stream) {
    const float* p0      = (const float*)d_in[0];
    const float* p1      = (const float*)d_in[1];
    const float* p2      = (const float*)d_in[2];
    const float* targets = (const float*)d_in[3];
    const float* anchors = (const float*)d_in[4];
    double* acc = (double*)d_ws;
    float*  out = (float*)d_out;

    hipMemsetAsync(d_ws, 0, 256, stream);
    main_kernel<<<NBLK, 256, 0, stream>>>(p0, p1, p2, targets, anchors, acc, out);
}

// Round 4
// 233.967 us; speedup vs baseline: 1.3319x; 1.3319x over previous
//
#include <hip/hip_runtime.h>
#include <math.h>

#define NT    300
#define NA    3
#define BATCH 16
#define NCLS  80
#define CCH   85
#define NROWS 2700            // 3 layers * 900 rows (a*NT+ti)
#define NBT   675             // target blocks: 4 waves/block, one ROW per WAVE
#define NBO   394             // obj blocks: 300 (L0) + 75 (L1) + 19 (L2)
#define NBLK  (NBT + NBO)
#define HASHSZ 4096

// ws layout (byte offsets):
//   0     : double obj_acc[3]      (atomicAdd of softplus partials)
//   64    : int done_cnt
//   256   : float row_lbox[2700]
//   11136 : float row_lcls[2700]
//   22016 : float row_nval[2700]
//   32896 : int   row_key [2700]   (-1 masked; else (li<<20)|cell)
//   43776 : float row_val [2700]   (objx * clip(ciou), scatter candidate)
// kernel_launch zeroes the first 256 B; row arrays are written unconditionally.

__device__ __forceinline__ float softplusf(float x) {
    // == max(x,0) + log1p(exp(-|x|)) == bce(x, 0)
    return fmaxf(x, 0.f) + log1pf(expf(-fabsf(x)));
}

// 256-thread block reduce; result valid on thread 0
__device__ __forceinline__ double block_reduce(double v, double* red) {
    #pragma unroll
    for (int off = 32; off > 0; off >>= 1) v += __shfl_down(v, off, 64);
    const int wid = threadIdx.x >> 6, lane = threadIdx.x & 63;
    if (lane == 0) red[wid] = v;
    __syncthreads();
    double r = (threadIdx.x < 4) ? red[threadIdx.x] : 0.0;
    r += __shfl_down(r, 2, 64);
    r += __shfl_down(r, 1, 64);
    __syncthreads();
    return r;
}

__global__ __launch_bounds__(256) void main_kernel(
    const float* __restrict__ p0, const float* __restrict__ p1,
    const float* __restrict__ p2,
    const float* __restrict__ targets, const float* __restrict__ anchors,
    char* __restrict__ ws, float* __restrict__ out)
{
    __shared__ double red[4];
    __shared__ int hkey[HASHSZ];
    __shared__ int hrow[HASHSZ];
    __shared__ bool amLast;

    double* obj_acc  = (double*)(ws);
    int*    done_cnt = (int*)(ws + 64);
    float*  row_lbox = (float*)(ws + 256);
    float*  row_lcls = (float*)(ws + 11136);
    float*  row_nval = (float*)(ws + 22016);
    int*    row_key  = (int*)(ws + 32896);
    float*  row_val  = (float*)(ws + 43776);

    if (blockIdx.x < NBT) {
        // ---------- per-target math: ONE ROW PER WAVE (coalesced 85-ch load) ----
        const int gr   = blockIdx.x * 4 + (threadIdx.x >> 6);   // global row
        const int lane = threadIdx.x & 63;
        const int li   = gr / (NA * NT);
        const int r    = gr - li * (NA * NT);                   // a*NT + ti
        const int a    = r / NT;
        const int ti   = r - a * NT;
        const float* p = (li == 0) ? p0 : ((li == 1) ? p1 : p2);
        const int W = 80 >> li, H = W;

        // wave-uniform scalars (broadcast loads, same address all lanes)
        const float img = targets[ti*6 + 0];
        const float cls = targets[ti*6 + 1];
        const float tx  = targets[ti*6 + 2] * (float)W;
        const float ty  = targets[ti*6 + 3] * (float)H;
        const float tw  = targets[ti*6 + 4] * (float)W;
        const float th  = targets[ti*6 + 5] * (float)H;

        const float ax = anchors[(li*3 + a)*2 + 0];
        const float ay = anchors[(li*3 + a)*2 + 1];
        const float rx = tw / ax, ry = th / ay;
        const float mr = fmaxf(fmaxf(rx, 1.f/rx), fmaxf(ry, 1.f/ry));
        const bool  mask = mr < 4.f;
        const float mf = mask ? 1.f : 0.f;

        const int b = (int)img;
        const int c = (int)cls;
        const int gij_x = (int)tx;      // trunc == floor (positive)
        const int gij_y = (int)ty;
        const int gi = min(max(gij_x, 0), W - 1);
        const int gj = min(max(gij_y, 0), H - 1);

        // reference quirk: anch = anchors[a, a] (layer-independent)
        const float anch_x = anchors[(a*3 + a)*2 + 0];
        const float anch_y = anchors[(a*3 + a)*2 + 1];

        const int match = BATCH - 1 - b;
        const int cell  = ((match*NA + a)*H + gj)*W + gi;
        const float* ps = p + (size_t)cell * CCH;

        // coalesced: 2 wave-load instructions cover all 85 channels
        const float x1 = ps[lane];                              // ch 0..63
        const float x2 = (lane < CCH - 64) ? ps[64 + lane] : 0.f; // ch 64..84

        const float s0   = __shfl(x1, 0);
        const float s1   = __shfl(x1, 1);
        const float s2   = __shfl(x1, 2);
        const float s3   = __shfl(x1, 3);
        const float objx = __shfl(x1, 4);

        // cls: sum_k softplus(ps[5+k]) - ps[5+c]
        const int ch = 5 + c;
        float contrib = (lane >= 5) ? softplusf(x1) : 0.f;
        if (lane < CCH - 64) contrib += softplusf(x2);
        if (lane == ch) contrib -= x1;
        if (ch >= 64 && lane == ch - 64) contrib -= x2;
        #pragma unroll
        for (int off = 32; off > 0; off >>= 1)
            contrib += __shfl_down(contrib, off, 64);           // lane 0 has sum

        // box math (wave-uniform)
        const float pxx = 1.f / (1.f + expf(-s0));
        const float pyy = 1.f / (1.f + expf(-s1));
        const float pw  = expf(s2) * anch_x;
        const float ph  = expf(s3) * anch_y;
        const float fx  = tx - (float)gij_x;
        const float fy  = ty - (float)gij_y;

        const float eps = 1e-9f;
        const float b1x1 = pxx - pw*0.5f, b1x2 = pxx + pw*0.5f;
        const float b1y1 = pyy - ph*0.5f, b1y2 = pyy + ph*0.5f;
        const float b2x1 = fx - tw*0.5f,  b2x2 = fx + tw*0.5f;
        const float b2y1 = fy - th*0.5f,  b2y2 = fy + th*0.5f;
        float iw = fminf(b1x2, b2x2) - fmaxf(b1x1, b2x1); iw = fmaxf(iw, 0.f);
        float ih = fminf(b1y2, b2y2) - fmaxf(b1y1, b2y1); ih = fmaxf(ih, 0.f);
        const float inter = iw * ih;
        const float w1 = b1x2 - b1x1, h1 = b1y2 - b1y1 + eps;
        const float w2 = b2x2 - b2x1, h2 = b2y2 - b2y1 + eps;
        const float uni = w1*h1 + w2*h2 - inter + eps;
        const float iou = inter / uni;
        const float cw = fmaxf(b1x2, b2x2) - fminf(b1x1, b2x1);
        const float chh = fmaxf(b1y2, b2y2) - fminf(b1y1, b2y1);
        const float c2 = cw*cw + chh*chh + eps;
        const float dx = b2x1 + b2x2 - b1x1 - b1x2;
        const float dy = b2y1 + b2y2 - b1y1 - b1y2;
        const float rho2 = (dx*dx + dy*dy) * 0.25f;
        const float dat = atanf(w2/h2) - atanf(w1/h1);
        const float v = 0.40528473456935108577f * dat * dat;    // 4/pi^2
        const float alpha = v / (1.f + eps - iou + v);
        const float ciou = iou - (rho2/c2 + v*alpha);

        if (lane == 0) {
            row_lbox[gr] = (1.f - ciou) * mf;
            row_lcls[gr] = contrib * mf;
            row_nval[gr] = mf;
            row_key[gr]  = mask ? ((li << 20) | cell) : -1;
            row_val[gr]  = mask ? objx * fmaxf(ciou, 0.f) : 0.f;
        }
    } else {
        // ---------- obj softplus sweep: 4 independent loads/thread ----------
        const int ob = blockIdx.x - NBT;
        int li, bb;
        if (ob < 300)      { li = 0; bb = ob; }
        else if (ob < 375) { li = 1; bb = ob - 300; }
        else               { li = 2; bb = ob - 375; }
        const float* p = (li == 0) ? p0 : ((li == 1) ? p1 : p2);
        const int N = (BATCH * NA * 6400) >> (2*li);   // 307200/76800/19200

        float s = 0.f;
        #pragma unroll
        for (int k = 0; k < 4; ++k) {
            const int idx = bb * 1024 + k * 256 + threadIdx.x;
            if (idx < N) s += softplusf(p[(size_t)idx * CCH + 4]);
        }
        const double t = block_reduce((double)s, red);
        if (threadIdx.x == 0) atomicAdd(&obj_acc[li], t);
    }

    // ---------- last block: dedup + reduce + finalize ----------
    if (threadIdx.x == 0) {
        __threadfence();
        amLast = (atomicAdd(done_cnt, 1) == NBLK - 1);
    }
    __syncthreads();
    if (!amLast) return;
    __threadfence();

    for (int q = threadIdx.x; q < HASHSZ; q += 256) { hkey[q] = -1; hrow[q] = -1; }
    __syncthreads();

    int    slots[11];
    int    nm = 0;
    double lb[3] = {0,0,0}, lc[3] = {0,0,0}, nv[3] = {0,0,0}, co[3] = {0,0,0};

    for (int i = threadIdx.x; i < NROWS; i += 256) {
        const int l = i / (NA * NT);
        lb[l] += (double)row_lbox[i];
        lc[l] += (double)row_lcls[i];
        nv[l] += (double)row_nval[i];
        const int k = row_key[i];
        int s = -1;
        if (k >= 0) {
            unsigned h = ((unsigned)k * 2654435761u) >> 20;
            s = (int)(h & (HASHSZ - 1));
            while (true) {
                const int prev = atomicCAS(&hkey[s], -1, k);
                if (prev == -1 || prev == k) { atomicMax(&hrow[s], i); break; }
                s = (s + 1) & (HASHSZ - 1);
            }
        }
        slots[nm++] = s;
    }
    __syncthreads();
    nm = 0;
    for (int i = threadIdx.x; i < NROWS; i += 256) {
        const int s = slots[nm++];
        if (s >= 0 && hrow[s] == i)          // last-wins winner of its cell
            co[i / (NA * NT)] += (double)row_val[i];
    }

    double rsum[12];
    #pragma unroll
    for (int l = 0; l < 3; ++l) {
        rsum[l*4 + 0] = block_reduce(lb[l], red);
        rsum[l*4 + 1] = block_reduce(lc[l], red);
        rsum[l*4 + 2] = block_reduce(co[l], red);
        rsum[l*4 + 3] = block_reduce(nv[l], red);
    }

    if (threadIdx.x == 0) {
        double lbox = 0.0, lobj = 0.0, lcls = 0.0;
        for (int l = 0; l < 3; ++l) {
            const double nvv = fmax(rsum[l*4 + 3], 1.0);
            lbox += rsum[l*4 + 0] / nvv;
            lcls += rsum[l*4 + 1] / (nvv * (double)NCLS);
            const double N = (double)((BATCH * NA * 6400) >> (2*l));
            lobj += (obj_acc[l] - rsum[l*4 + 2]) / N;
        }
        lbox *= 0.05;
        lcls *= 0.5;
        const double loss = lbox + lobj + lcls;
        out[0] = (float)loss;
        out[1] = (float)lbox;
        out[2] = (float)lobj;
        out[3] = (float)lcls;
        out[4] = (float)loss;
    }
}

extern "C" void kernel_launch(void* const* d_in, const int* in_sizes, int n_in,
                              void* d_out, int out_size, void* d_ws, size_t ws_size,
                              hipStream_t stream) {
    const float* p0      = (const float*)d_in[0];
    const float* p1      = (const float*)d_in[1];
    const float* p2      = (const float*)d_in[2];
    const float* targets = (const float*)d_in[3];
    const float* anchors = (const float*)d_in[4];

    hipMemsetAsync(d_ws, 0, 256, stream);
    main_kernel<<<NBLK, 256, 0, stream>>>(p0, p1, p2, targets, anchors,
                                          (char*)d_ws, (float*)d_out);
}

// Round 5
// 182.094 us; speedup vs baseline: 1.7114x; 1.2849x over previous
//
#include <hip/hip_runtime.h>
#include <math.h>

#define NT    300
#define NA    3
#define BATCH 16
#define NCLS  80
#define CCH   85
#define NROWS 2700            // 3 layers * 900 rows (a*NT+ti)
#define NBO   394             // obj blocks: 300 (L0) + 75 (L1) + 19 (L2)
#define NBT   675             // target blocks: 4 waves/block, one ROW per WAVE
#define NBLK  (NBO + NBT)
#define HASHSZ 4096

// ws layout (byte offsets) — every slot written unconditionally by main_kernel,
// so NO pre-zeroing (and no memset dispatch) is needed:
//   0     : double obj_part[NBO]   per-obj-block softplus partial
//   3200  : float row_lbox[2700]
//   14000 : float row_lcls[2700]
//   24800 : float row_nval[2700]
//   35600 : int   row_key [2700]   (-1 masked; else (li<<20)|cell, cell<2^19)
//   46400 : float row_val [2700]   (objx * clip(ciou), scatter candidate)

__device__ __forceinline__ float softplusf(float x) {
    // == max(x,0) + log1p(exp(-|x|)) == bce(x, 0)
    return fmaxf(x, 0.f) + log1pf(expf(-fabsf(x)));
}

// 256-thread block reduce; result valid on thread 0
__device__ __forceinline__ double block_reduce(double v, double* red) {
    #pragma unroll
    for (int off = 32; off > 0; off >>= 1) v += __shfl_down(v, off, 64);
    const int wid = threadIdx.x >> 6, lane = threadIdx.x & 63;
    if (lane == 0) red[wid] = v;
    __syncthreads();
    double r = (threadIdx.x < 4) ? red[threadIdx.x] : 0.0;
    r += __shfl_down(r, 2, 64);
    r += __shfl_down(r, 1, 64);
    __syncthreads();
    return r;
}

__global__ __launch_bounds__(256) void main_kernel(
    const float* __restrict__ p0, const float* __restrict__ p1,
    const float* __restrict__ p2,
    const float* __restrict__ targets, const float* __restrict__ anchors,
    char* __restrict__ ws)
{
    __shared__ double red[4];

    double* obj_part = (double*)(ws);
    float*  row_lbox = (float*)(ws + 3200);
    float*  row_lcls = (float*)(ws + 14000);
    float*  row_nval = (float*)(ws + 24800);
    int*    row_key  = (int*)(ws + 35600);
    float*  row_val  = (float*)(ws + 46400);

    if (blockIdx.x < NBO) {
        // ---------- obj softplus sweep: 4 independent loads/thread ----------
        const int ob = blockIdx.x;
        int li, bb;
        if (ob < 300)      { li = 0; bb = ob; }
        else if (ob < 375) { li = 1; bb = ob - 300; }
        else               { li = 2; bb = ob - 375; }
        const float* p = (li == 0) ? p0 : ((li == 1) ? p1 : p2);
        const int N = (BATCH * NA * 6400) >> (2*li);   // 307200/76800/19200

        float s = 0.f;
        #pragma unroll
        for (int k = 0; k < 4; ++k) {
            const int idx = bb * 1024 + k * 256 + threadIdx.x;
            if (idx < N) s += softplusf(p[(size_t)idx * CCH + 4]);
        }
        const double t = block_reduce((double)s, red);
        if (threadIdx.x == 0) obj_part[ob] = t;
        return;
    }

    // ---------- per-target math: ONE ROW PER WAVE (coalesced 85-ch load) ----
    const int gr   = (blockIdx.x - NBO) * 4 + (threadIdx.x >> 6); // global row
    const int lane = threadIdx.x & 63;
    const int li   = gr / (NA * NT);
    const int r    = gr - li * (NA * NT);                   // a*NT + ti
    const int a    = r / NT;
    const int ti   = r - a * NT;
    const float* p = (li == 0) ? p0 : ((li == 1) ? p1 : p2);
    const int W = 80 >> li, H = W;

    // wave-uniform scalars (broadcast loads)
    const float img = targets[ti*6 + 0];
    const float cls = targets[ti*6 + 1];
    const float tx  = targets[ti*6 + 2] * (float)W;
    const float ty  = targets[ti*6 + 3] * (float)H;
    const float tw  = targets[ti*6 + 4] * (float)W;
    const float th  = targets[ti*6 + 5] * (float)H;

    const float ax = anchors[(li*3 + a)*2 + 0];
    const float ay = anchors[(li*3 + a)*2 + 1];
    const float rx = tw / ax, ry = th / ay;
    const float mr = fmaxf(fmaxf(rx, 1.f/rx), fmaxf(ry, 1.f/ry));
    const bool  mask = mr < 4.f;
    const float mf = mask ? 1.f : 0.f;

    const int b = (int)img;
    const int c = (int)cls;
    const int gij_x = (int)tx;          // trunc == floor (positive)
    const int gij_y = (int)ty;
    const int gi = min(max(gij_x, 0), W - 1);
    const int gj = min(max(gij_y, 0), H - 1);

    // reference quirk: anch = anchors[a, a] (layer-independent)
    const float anch_x = anchors[(a*3 + a)*2 + 0];
    const float anch_y = anchors[(a*3 + a)*2 + 1];

    const int match = BATCH - 1 - b;
    const int cell  = ((match*NA + a)*H + gj)*W + gi;
    const float* ps = p + (size_t)cell * CCH;

    // coalesced: 2 wave-load instructions cover all 85 channels
    const float x1 = ps[lane];                                // ch 0..63
    const float x2 = (lane < CCH - 64) ? ps[64 + lane] : 0.f; // ch 64..84

    const float s0   = __shfl(x1, 0);
    const float s1   = __shfl(x1, 1);
    const float s2   = __shfl(x1, 2);
    const float s3   = __shfl(x1, 3);
    const float objx = __shfl(x1, 4);

    // cls: sum_k softplus(ps[5+k]) - ps[5+c]
    const int ch = 5 + c;
    float contrib = (lane >= 5) ? softplusf(x1) : 0.f;
    if (lane < CCH - 64) contrib += softplusf(x2);
    if (lane == ch) contrib -= x1;
    if (ch >= 64 && lane == ch - 64) contrib -= x2;
    #pragma unroll
    for (int off = 32; off > 0; off >>= 1)
        contrib += __shfl_down(contrib, off, 64);             // lane 0 has sum

    // box math (wave-uniform)
    const float pxx = 1.f / (1.f + expf(-s0));
    const float pyy = 1.f / (1.f + expf(-s1));
    const float pw  = expf(s2) * anch_x;
    const float ph  = expf(s3) * anch_y;
    const float fx  = tx - (float)gij_x;
    const float fy  = ty - (float)gij_y;

    const float eps = 1e-9f;
    const float b1x1 = pxx - pw*0.5f, b1x2 = pxx + pw*0.5f;
    const float b1y1 = pyy - ph*0.5f, b1y2 = pyy + ph*0.5f;
    const float b2x1 = fx - tw*0.5f,  b2x2 = fx + tw*0.5f;
    const float b2y1 = fy - th*0.5f,  b2y2 = fy + th*0.5f;
    float iw = fminf(b1x2, b2x2) - fmaxf(b1x1, b2x1); iw = fmaxf(iw, 0.f);
    float ih = fminf(b1y2, b2y2) - fmaxf(b1y1, b2y1); ih = fmaxf(ih, 0.f);
    const float inter = iw * ih;
    const float w1 = b1x2 - b1x1, h1 = b1y2 - b1y1 + eps;
    const float w2 = b2x2 - b2x1, h2 = b2y2 - b2y1 + eps;
    const float uni = w1*h1 + w2*h2 - inter + eps;
    const float iou = inter / uni;
    const float cw  = fmaxf(b1x2, b2x2) - fminf(b1x1, b2x1);
    const float chh = fmaxf(b1y2, b2y2) - fminf(b1y1, b2y1);
    const float c2 = cw*cw + chh*chh + eps;
    const float dx = b2x1 + b2x2 - b1x1 - b1x2;
    const float dy = b2y1 + b2y2 - b1y1 - b1y2;
    const float rho2 = (dx*dx + dy*dy) * 0.25f;
    const float dat = atanf(w2/h2) - atanf(w1/h1);
    const float v = 0.40528473456935108577f * dat * dat;      // 4/pi^2
    const float alpha = v / (1.f + eps - iou + v);
    const float ciou = iou - (rho2/c2 + v*alpha);

    if (lane == 0) {
        row_lbox[gr] = (1.f - ciou) * mf;
        row_lcls[gr] = contrib * mf;
        row_nval[gr] = mf;
        row_key[gr]  = mask ? ((li << 20) | cell) : -1;
        row_val[gr]  = mask ? objx * fmaxf(ciou, 0.f) : 0.f;
    }
}

__global__ __launch_bounds__(256) void final_kernel(
    const char* __restrict__ ws, float* __restrict__ out)
{
    __shared__ double red[4];
    __shared__ int hkey[HASHSZ];
    __shared__ int hrow[HASHSZ];

    const double* obj_part = (const double*)(ws);
    const float*  row_lbox = (const float*)(ws + 3200);
    const float*  row_lcls = (const float*)(ws + 14000);
    const float*  row_nval = (const float*)(ws + 24800);
    const int*    row_key  = (const int*)(ws + 35600);
    const float*  row_val  = (const float*)(ws + 46400);

    for (int q = threadIdx.x; q < HASHSZ; q += 256) { hkey[q] = -1; hrow[q] = -1; }
    __syncthreads();

    // obj softplus sums per layer
    double so[3] = {0, 0, 0};
    for (int bk = threadIdx.x; bk < NBO; bk += 256) {
        const double v = obj_part[bk];
        if (bk < 300)      so[0] += v;
        else if (bk < 375) so[1] += v;
        else               so[2] += v;
    }

    // row sums + last-wins hash insert
    int    slots[11];
    int    nm = 0;
    double lb[3] = {0,0,0}, lc[3] = {0,0,0}, nv[3] = {0,0,0}, co[3] = {0,0,0};

    for (int i = threadIdx.x; i < NROWS; i += 256) {
        const int l = i / (NA * NT);
        lb[l] += (double)row_lbox[i];
        lc[l] += (double)row_lcls[i];
        nv[l] += (double)row_nval[i];
        const int k = row_key[i];
        int s = -1;
        if (k >= 0) {
            unsigned h = ((unsigned)k * 2654435761u) >> 20;
            s = (int)(h & (HASHSZ - 1));
            while (true) {
                const int prev = atomicCAS(&hkey[s], -1, k);
                if (prev == -1 || prev == k) { atomicMax(&hrow[s], i); break; }
                s = (s + 1) & (HASHSZ - 1);
            }
        }
        slots[nm++] = s;
    }
    __syncthreads();
    nm = 0;
    for (int i = threadIdx.x; i < NROWS; i += 256) {
        const int s = slots[nm++];
        if (s >= 0 && hrow[s] == i)          // last-wins winner of its cell
            co[i / (NA * NT)] += (double)row_val[i];
    }

    double rsum[12];
    #pragma unroll
    for (int l = 0; l < 3; ++l) {
        rsum[l*4 + 0] = block_reduce(lb[l], red);
        rsum[l*4 + 1] = block_reduce(lc[l], red);
        rsum[l*4 + 2] = block_reduce(co[l], red);
        rsum[l*4 + 3] = block_reduce(nv[l], red);
        so[l]         = block_reduce(so[l], red);
    }

    if (threadIdx.x == 0) {
        double lbox = 0.0, lobj = 0.0, lcls = 0.0;
        for (int l = 0; l < 3; ++l) {
            const double nvv = fmax(rsum[l*4 + 3], 1.0);
            lbox += rsum[l*4 + 0] / nvv;
            lcls += rsum[l*4 + 1] / (nvv * (double)NCLS);
            const double N = (double)((BATCH * NA * 6400) >> (2*l));
            lobj += (so[l] - rsum[l*4 + 2]) / N;
        }
        lbox *= 0.05;
        lcls *= 0.5;
        const double loss = lbox + lobj + lcls;
        out[0] = (float)loss;
        out[1] = (float)lbox;
        out[2] = (float)lobj;
        out[3] = (float)lcls;
        out[4] = (float)loss;
    }
}

extern "C" void kernel_launch(void* const* d_in, const int* in_sizes, int n_in,
                              void* d_out, int out_size, void* d_ws, size_t ws_size,
                              hipStream_t stream) {
    const float* p0      = (const float*)d_in[0];
    const float* p1      = (const float*)d_in[1];
    const float* p2      = (const float*)d_in[2];
    const float* targets = (const float*)d_in[3];
    const float* anchors = (const float*)d_in[4];

    main_kernel<<<NBLK, 256, 0, stream>>>(p0, p1, p2, targets, anchors,
                                          (char*)d_ws);
    final_kernel<<<1, 256, 0, stream>>>((const char*)d_ws, (float*)d_out);
}